// Round 1
// baseline (566.414 us; speedup 1.0000x reference)
//
#include <hip/hip_runtime.h>
#include <math.h>

// ProbAttention (Informer ProbSparse) — B=8 L=2048 H=8 D=64 u=40
// q/k/v reshape(B,H,L,D) is a flat reinterpretation -> treat as (BH=64, L, D) contiguous.
#define LSEQ 2048
#define DDIM 64
#define UU   40
#define NBH  64
#define CTX_ELEMS (NBH*UU*DDIM)   // 163840
#define ATTN_ELEMS (NBH*UU*LSEQ)  // 5242880  (== NBH*LSEQ*UU, reused as QK_sample scratch)

// ---------------- K1: QK_sample[bh,l,s] = q[bh,l,:] . k[bh,idx[l,s],:] ----------------
// one thread per dot; tid = (bh*L + l)*U + s; writes coalesced into attn region (scratch)
__global__ __launch_bounds__(256) void k1_qk_sample(
    const float* __restrict__ q, const float* __restrict__ k,
    const int* __restrict__ idxs, float* __restrict__ qk) {
  int tid = blockIdx.x * 256 + threadIdx.x;        // exactly NBH*LSEQ*UU threads
  int s  = tid % UU;
  int l  = (tid / UU) % LSEQ;
  int bh = tid / (UU * LSEQ);
  int j  = idxs[l * UU + s];
  const float4* qr = (const float4*)(q + (size_t)(bh * LSEQ + l) * DDIM);
  const float4* kr = (const float4*)(k + (size_t)(bh * LSEQ + j) * DDIM);
  float acc = 0.f;
#pragma unroll
  for (int i = 0; i < 16; ++i) {
    float4 a = qr[i], b = kr[i];
    acc += a.x * b.x + a.y * b.y + a.z * b.z + a.w * b.w;
  }
  qk[tid] = acc;
}

// ---------------- K2: M[bh,l] = max_s qk - sum_s qk / L ----------------
__global__ __launch_bounds__(256) void k2_m(const float* __restrict__ qk,
                                            float* __restrict__ M) {
  int t = blockIdx.x * 256 + threadIdx.x;          // NBH*LSEQ threads
  const float* row = qk + (size_t)t * UU;
  float mx = -INFINITY, sm = 0.f;
#pragma unroll
  for (int s = 0; s < UU; ++s) {
    float v = row[s];
    mx = fmaxf(mx, v);
    sm += v;
  }
  M[t] = mx - sm * (1.0f / (float)LSEQ);
}

// ---------------- K3: top-40 indices per head (desc value, tie -> smaller index) -------
__global__ __launch_bounds__(256) void k3_topk(const float* __restrict__ M,
                                               int* __restrict__ Mtop) {
  __shared__ float vals[LSEQ];
  __shared__ float rv[256];
  __shared__ int   ri[256];
  int bh = blockIdx.x;
  int t  = threadIdx.x;
  for (int i = t; i < LSEQ; i += 256) vals[i] = M[bh * LSEQ + i];
  __syncthreads();
  for (int it = 0; it < UU; ++it) {
    float bv = -INFINITY; int bi = 0;
    for (int i = t; i < LSEQ; i += 256) {
      float v = vals[i];
      if (v > bv || (v == bv && i < bi)) { bv = v; bi = i; }
    }
    rv[t] = bv; ri[t] = bi;
    __syncthreads();
    for (int off = 128; off > 0; off >>= 1) {
      if (t < off) {
        float ov = rv[t + off]; int oi = ri[t + off];
        if (ov > rv[t] || (ov == rv[t] && oi < ri[t])) { rv[t] = ov; ri[t] = oi; }
      }
      __syncthreads();
    }
    if (t == 0) { Mtop[bh * UU + it] = ri[0]; vals[ri[0]] = -INFINITY; }
    __syncthreads();
  }
}

// ---------------- K4: scores[bh,u,l] = scale * q[Mtop[u]] . k[l] -----------------------
// block = (bh, l-chunk of 256); thread keeps its k row in regs, loops u (q row scalarizes)
__global__ __launch_bounds__(256) void k4_scores(
    const float* __restrict__ q, const float* __restrict__ k,
    const int* __restrict__ Mtop, float* __restrict__ attn) {
  int bh    = blockIdx.x >> 3;
  int chunk = blockIdx.x & 7;
  int l     = chunk * 256 + threadIdx.x;
  const float4* kr = (const float4*)(k + (size_t)(bh * LSEQ + l) * DDIM);
  float4 kv[16];
#pragma unroll
  for (int i = 0; i < 16; ++i) kv[i] = kr[i];
  for (int u = 0; u < UU; ++u) {
    int qi = __builtin_amdgcn_readfirstlane(Mtop[bh * UU + u]);
    const float4* qr = (const float4*)(q + (size_t)(bh * LSEQ + qi) * DDIM);
    float acc = 0.f;
#pragma unroll
    for (int i = 0; i < 16; ++i) {
      float4 a = qr[i], b = kv[i];
      acc += a.x * b.x + a.y * b.y + a.z * b.z + a.w * b.w;
    }
    attn[(size_t)(bh * UU + u) * LSEQ + l] = acc * 0.125f;  // 1/sqrt(64)
  }
}

// ---------------- K5: softmax over l for each (bh,u) row, in place ---------------------
__global__ __launch_bounds__(256) void k5_softmax(float* __restrict__ attn) {
  __shared__ float red[256];
  int row = blockIdx.x;                       // NBH*UU rows
  float* p = attn + (size_t)row * LSEQ;
  int t = threadIdx.x;
  float v[8];
  float mx = -INFINITY;
#pragma unroll
  for (int i = 0; i < 8; ++i) { v[i] = p[t + 256 * i]; mx = fmaxf(mx, v[i]); }
  red[t] = mx; __syncthreads();
  for (int off = 128; off > 0; off >>= 1) {
    if (t < off) red[t] = fmaxf(red[t], red[t + off]);
    __syncthreads();
  }
  mx = red[0]; __syncthreads();
  float sm = 0.f;
#pragma unroll
  for (int i = 0; i < 8; ++i) { v[i] = __expf(v[i] - mx); sm += v[i]; }
  red[t] = sm; __syncthreads();
  for (int off = 128; off > 0; off >>= 1) {
    if (t < off) red[t] += red[t + off];
    __syncthreads();
  }
  float inv = 1.0f / red[0];
#pragma unroll
  for (int i = 0; i < 8; ++i) p[t + 256 * i] = v[i] * inv;
}

// ---------------- K6: zero context region (d_out poisoned each call) -------------------
__global__ __launch_bounds__(256) void k6_zero(float* __restrict__ ctx) {
  int t = blockIdx.x * 256 + threadIdx.x;
  if (t < CTX_ELEMS) ctx[t] = 0.f;
}

// ---------------- K7: context[bh,u,d] = sum_l attn[bh,u,l] * v[bh,l,d] -----------------
// block = (bh, l-chunk of 256); thread = (wave w = l-subchunk, lane d); partials -> atomicAdd
__global__ __launch_bounds__(256) void k7_context(
    const float* __restrict__ attn, const float* __restrict__ v,
    float* __restrict__ ctx) {
  int bh    = blockIdx.x >> 3;
  int chunk = blockIdx.x & 7;
  int t = threadIdx.x;
  int d = t & 63;
  int w = t >> 6;                 // 4 waves, each owns 64 consecutive l
  float acc[UU];
#pragma unroll
  for (int u = 0; u < UU; ++u) acc[u] = 0.f;
  int lbase = chunk * 256 + w * 64;
  for (int i = 0; i < 64; ++i) {
    int lu = __builtin_amdgcn_readfirstlane(lbase + i);   // wave-uniform l -> s_load attn
    float vv = v[(size_t)(bh * LSEQ + lu) * DDIM + d];
#pragma unroll
    for (int u = 0; u < UU; ++u) {
      acc[u] = fmaf(attn[(size_t)(bh * UU + u) * LSEQ + lu], vv, acc[u]);
    }
  }
#pragma unroll
  for (int u = 0; u < UU; ++u)
    atomicAdd(&ctx[(size_t)(bh * UU + u) * DDIM + d], acc[u]);
}

extern "C" void kernel_launch(void* const* d_in, const int* in_sizes, int n_in,
                              void* d_out, int out_size, void* d_ws, size_t ws_size,
                              hipStream_t stream) {
  const float* q   = (const float*)d_in[0];
  const float* k   = (const float*)d_in[1];
  const float* v   = (const float*)d_in[2];
  const int*   idx = (const int*)d_in[3];

  float* ctx  = (float*)d_out;                  // [NBH, UU, DDIM]
  float* attn = (float*)d_out + CTX_ELEMS;      // [NBH, UU, LSEQ]; also QK_sample scratch

  float* M    = (float*)d_ws;                               // NBH*LSEQ floats (512 KB)
  int*   Mtop = (int*)((char*)d_ws + (size_t)NBH * LSEQ * 4); // NBH*UU ints

  k1_qk_sample<<<ATTN_ELEMS / 256, 256, 0, stream>>>(q, k, idx, attn);
  k2_m<<<(NBH * LSEQ) / 256, 256, 0, stream>>>(attn, M);
  k3_topk<<<NBH, 256, 0, stream>>>(M, Mtop);
  k4_scores<<<NBH * 8, 256, 0, stream>>>(q, k, Mtop, attn);
  k5_softmax<<<NBH * UU, 256, 0, stream>>>(attn);
  k6_zero<<<(CTX_ELEMS + 255) / 256, 256, 0, stream>>>(ctx);
  k7_context<<<NBH * 8, 256, 0, stream>>>(attn, v, ctx);
}

// Round 2
// 500.354 us; speedup vs baseline: 1.1320x; 1.1320x over previous
//
#include <hip/hip_runtime.h>
#include <math.h>

// ProbAttention (Informer ProbSparse) — B=8 L=2048 H=8 D=64 u=40
// q/k/v reshape(B,H,L,D) is a flat reinterpretation -> treat as (BH=64, L, D) contiguous.
#define LSEQ 2048
#define DDIM 64
#define UU   40
#define NBH  64
#define CTX_ELEMS (NBH*UU*DDIM)   // 163840

// ---------------- K12: fused QK_sample + M ----------------
// thread per (bh,l): q row in regs, loop 40 sampled k rows (2-way interleave),
// M[bh,l] = max_s dot - sum_s dot / L.  Grid swizzled: bh = b&63 so one head's
// blocks share an XCD (k working set 8 heads x 512KB per XCD L2).
__global__ __launch_bounds__(256) void k12_sample_m(
    const float* __restrict__ q, const float* __restrict__ k,
    const int* __restrict__ idxs, float* __restrict__ M) {
  int b = blockIdx.x;               // 512 blocks
  int bh = b & 63;
  int chunk = b >> 6;
  int l = chunk * 256 + threadIdx.x;

  const float4* qr = (const float4*)(q + (size_t)(bh * LSEQ + l) * DDIM);
  float4 qv[16];
#pragma unroll
  for (int i = 0; i < 16; ++i) qv[i] = qr[i];

  const float* kbase = k + (size_t)bh * LSEQ * DDIM;
  const int2* ir2 = (const int2*)(idxs + l * UU);   // 160B-aligned

  float mx = -INFINITY, sm = 0.f;
#pragma unroll 1
  for (int s2 = 0; s2 < UU / 2; ++s2) {
    int2 jv = ir2[s2];
    const float4* k0 = (const float4*)(kbase + (size_t)jv.x * DDIM);
    const float4* k1 = (const float4*)(kbase + (size_t)jv.y * DDIM);
    float a0[4] = {0.f, 0.f, 0.f, 0.f};
    float a1[4] = {0.f, 0.f, 0.f, 0.f};
#pragma unroll
    for (int i = 0; i < 16; ++i) {
      float4 x = qv[i];
      float4 y0 = k0[i];
      float4 y1 = k1[i];
      a0[i & 3] += x.x * y0.x + x.y * y0.y + x.z * y0.z + x.w * y0.w;
      a1[i & 3] += x.x * y1.x + x.y * y1.y + x.z * y1.z + x.w * y1.w;
    }
    float d0 = (a0[0] + a0[1]) + (a0[2] + a0[3]);
    float d1 = (a1[0] + a1[1]) + (a1[2] + a1[3]);
    mx = fmaxf(mx, d0); sm += d0;
    mx = fmaxf(mx, d1); sm += d1;
  }
  M[bh * LSEQ + l] = mx - sm * (1.0f / (float)LSEQ);
}

// ---------------- K3: top-40 per head, one wave per block ----------------
// desc value, tie -> smaller index (matches jax.lax.top_k stability)
__global__ __launch_bounds__(64) void k3_topk(const float* __restrict__ M,
                                              int* __restrict__ Mtop) {
  __shared__ float vals[LSEQ];
  int bh = blockIdx.x;
  int t = threadIdx.x;
  for (int i = t; i < LSEQ; i += 64) vals[i] = M[bh * LSEQ + i];
  __syncthreads();
  for (int it = 0; it < UU; ++it) {
    float bv = -INFINITY; int bi = 0x7fffffff;
    for (int i = t; i < LSEQ; i += 64) {
      float v = vals[i];
      if (v > bv) { bv = v; bi = i; }   // lane scans ascending i: first (smallest) wins ties
    }
#pragma unroll
    for (int off = 32; off > 0; off >>= 1) {
      float ov = __shfl_xor(bv, off, 64);
      int   oi = __shfl_xor(bi, off, 64);
      if (ov > bv || (ov == bv && oi < bi)) { bv = ov; bi = oi; }
    }
    if (t == 0) { Mtop[bh * UU + it] = bi; vals[bi] = -INFINITY; }
    __syncthreads();
  }
}

// ---------------- K4: scores[bh,u,l] = scale * q[Mtop[u]] . k[l] ----------------
__global__ __launch_bounds__(256) void k4_scores(
    const float* __restrict__ q, const float* __restrict__ k,
    const int* __restrict__ Mtop, float* __restrict__ attn) {
  int b = blockIdx.x;               // 512 blocks, same swizzle as k12
  int bh = b & 63;
  int chunk = b >> 6;
  int l = chunk * 256 + threadIdx.x;
  const float4* kr = (const float4*)(k + (size_t)(bh * LSEQ + l) * DDIM);
  float4 kv[16];
#pragma unroll
  for (int i = 0; i < 16; ++i) kv[i] = kr[i];
  for (int u = 0; u < UU; ++u) {
    int qi = __builtin_amdgcn_readfirstlane(Mtop[bh * UU + u]);
    const float4* qr = (const float4*)(q + (size_t)(bh * LSEQ + qi) * DDIM);
    float a0 = 0.f, a1 = 0.f, a2 = 0.f, a3 = 0.f;
#pragma unroll
    for (int i = 0; i < 16; i += 4) {
      float4 x0 = qr[i], x1 = qr[i+1], x2 = qr[i+2], x3 = qr[i+3];
      float4 y0 = kv[i], y1 = kv[i+1], y2 = kv[i+2], y3 = kv[i+3];
      a0 += x0.x*y0.x + x0.y*y0.y + x0.z*y0.z + x0.w*y0.w;
      a1 += x1.x*y1.x + x1.y*y1.y + x1.z*y1.z + x1.w*y1.w;
      a2 += x2.x*y2.x + x2.y*y2.y + x2.z*y2.z + x2.w*y2.w;
      a3 += x3.x*y3.x + x3.y*y3.y + x3.z*y3.z + x3.w*y3.w;
    }
    attn[(size_t)(bh * UU + u) * LSEQ + l] = ((a0+a1)+(a2+a3)) * 0.125f;
  }
}

// ---------------- K5: softmax over l for each (bh,u) row, in place ----------------
__global__ __launch_bounds__(256) void k5_softmax(float* __restrict__ attn) {
  __shared__ float red[256];
  int row = blockIdx.x;                       // NBH*UU rows
  float* p = attn + (size_t)row * LSEQ;
  int t = threadIdx.x;
  float v[8];
  float mx = -INFINITY;
#pragma unroll
  for (int i = 0; i < 8; ++i) { v[i] = p[t + 256 * i]; mx = fmaxf(mx, v[i]); }
  red[t] = mx; __syncthreads();
  for (int off = 128; off > 0; off >>= 1) {
    if (t < off) red[t] = fmaxf(red[t], red[t + off]);
    __syncthreads();
  }
  mx = red[0]; __syncthreads();
  float sm = 0.f;
#pragma unroll
  for (int i = 0; i < 8; ++i) { v[i] = __expf(v[i] - mx); sm += v[i]; }
  red[t] = sm; __syncthreads();
  for (int off = 128; off > 0; off >>= 1) {
    if (t < off) red[t] += red[t + off];
    __syncthreads();
  }
  float inv = 1.0f / red[0];
#pragma unroll
  for (int i = 0; i < 8; ++i) p[t + 256 * i] = v[i] * inv;
}

// ---------------- K7: context[bh,u,d] = sum_l attn[bh,u,l] * v[bh,l,d] ----------------
// block per (bh, ugroup of 10): 256 blocks. 4 waves partition l into 512-strips;
// lane = d. attn loads are wave-uniform float4 (scalarize to s_load); v coalesced.
// Cross-wave reduce in LDS, single store — no atomics, no zero-init needed.
__global__ __launch_bounds__(256) void k7_context(
    const float* __restrict__ attn, const float* __restrict__ v,
    float* __restrict__ ctx) {
  int b = blockIdx.x;
  int bh = b & 63;
  int ug = b >> 6;                  // 0..3, u in [ug*10, ug*10+10)
  int t = threadIdx.x;
  int d = t & 63;
  int w = t >> 6;
  const float* vb = v + (size_t)bh * LSEQ * DDIM;
  const float* ab = attn + (size_t)(bh * UU + ug * 10) * LSEQ;
  float acc[10];
#pragma unroll
  for (int u = 0; u < 10; ++u) acc[u] = 0.f;
  int l0 = w * 512;
#pragma unroll 1
  for (int l4 = 0; l4 < 128; ++l4) {
    int l = l0 + l4 * 4;
    float4 av[10];
#pragma unroll
    for (int u = 0; u < 10; ++u)
      av[u] = *(const float4*)(ab + (size_t)u * LSEQ + l);   // wave-uniform -> s_load
#pragma unroll
    for (int i = 0; i < 4; ++i) {
      float vv = vb[(size_t)(l + i) * DDIM + d];
      const float* af = (const float*)av;
#pragma unroll
      for (int u = 0; u < 10; ++u)
        acc[u] = fmaf(af[u * 4 + i], vv, acc[u]);
    }
  }
  __shared__ float red[4][10][64];  // 10.2 KB
#pragma unroll
  for (int u = 0; u < 10; ++u) red[w][u][d] = acc[u];
  __syncthreads();
  if (w == 0) {
#pragma unroll
    for (int u = 0; u < 10; ++u) {
      float s = red[0][u][d] + red[1][u][d] + red[2][u][d] + red[3][u][d];
      ctx[(size_t)(bh * UU + ug * 10 + u) * DDIM + d] = s;
    }
  }
}

extern "C" void kernel_launch(void* const* d_in, const int* in_sizes, int n_in,
                              void* d_out, int out_size, void* d_ws, size_t ws_size,
                              hipStream_t stream) {
  const float* q   = (const float*)d_in[0];
  const float* k   = (const float*)d_in[1];
  const float* v   = (const float*)d_in[2];
  const int*   idx = (const int*)d_in[3];

  float* ctx  = (float*)d_out;                  // [NBH, UU, DDIM]
  float* attn = (float*)d_out + CTX_ELEMS;      // [NBH, UU, LSEQ]

  float* M    = (float*)d_ws;                                 // NBH*LSEQ floats
  int*   Mtop = (int*)((char*)d_ws + (size_t)NBH * LSEQ * 4); // NBH*UU ints

  k12_sample_m<<<NBH * 8, 256, 0, stream>>>(q, k, idx, M);
  k3_topk<<<NBH, 64, 0, stream>>>(M, Mtop);
  k4_scores<<<NBH * 8, 256, 0, stream>>>(q, k, Mtop, attn);
  k5_softmax<<<NBH * UU, 256, 0, stream>>>(attn);
  k7_context<<<NBH * 4, 256, 0, stream>>>(attn, v, ctx);
}

// Round 3
// 442.126 us; speedup vs baseline: 1.2811x; 1.1317x over previous
//
#include <hip/hip_runtime.h>
#include <math.h>

// ProbAttention (Informer ProbSparse) — B=8 L=2048 H=8 D=64 u=40
// q/k/v reshape(B,H,L,D) is a flat reinterpretation -> treat as (BH=64, L, D) contiguous.
#define LSEQ 2048
#define DDIM 64
#define UU   40
#define NBH  64
#define CTX_ELEMS (NBH*UU*DDIM)   // 163840

// ---------------- K12: QK_sample partial (20 samples) -> (max, sum) ----------------
// grid 1024: bh = b&63 (XCD swizzle), l-chunk = (b>>6)&7, s-half = b>>9.
// __launch_bounds__(256,4): cap VGPR at 128 so grid's 16 waves/CU actually fit.
__global__ __launch_bounds__(256, 4) void k12_sample_m(
    const float* __restrict__ q, const float* __restrict__ k,
    const int* __restrict__ idxs, float* __restrict__ pmx, float* __restrict__ psm) {
  int b = blockIdx.x;
  int bh = b & 63;
  int chunk = (b >> 6) & 7;
  int h = b >> 9;                   // s-half: 0 or 1
  int l = chunk * 256 + threadIdx.x;

  const float4* qr = (const float4*)(q + (size_t)(bh * LSEQ + l) * DDIM);
  float4 qv[16];
#pragma unroll
  for (int i = 0; i < 16; ++i) qv[i] = qr[i];

  const float* kbase = k + (size_t)bh * LSEQ * DDIM;
  const int2* ir2 = (const int2*)(idxs + l * UU + h * 20);   // 8B-aligned

  float mx = -INFINITY, sm = 0.f;
#pragma unroll 1
  for (int s2 = 0; s2 < 10; ++s2) {
    int2 jv = ir2[s2];
    const float4* k0 = (const float4*)(kbase + (size_t)jv.x * DDIM);
    const float4* k1 = (const float4*)(kbase + (size_t)jv.y * DDIM);
    float a0[4] = {0.f, 0.f, 0.f, 0.f};
    float a1[4] = {0.f, 0.f, 0.f, 0.f};
#pragma unroll
    for (int i = 0; i < 16; ++i) {
      float4 x = qv[i];
      float4 y0 = k0[i];
      float4 y1 = k1[i];
      a0[i & 3] += x.x * y0.x + x.y * y0.y + x.z * y0.z + x.w * y0.w;
      a1[i & 3] += x.x * y1.x + x.y * y1.y + x.z * y1.z + x.w * y1.w;
    }
    float d0 = (a0[0] + a0[1]) + (a0[2] + a0[3]);
    float d1 = (a1[0] + a1[1]) + (a1[2] + a1[3]);
    mx = fmaxf(mx, d0); sm += d0;
    mx = fmaxf(mx, d1); sm += d1;
  }
  pmx[h * (NBH * LSEQ) + bh * LSEQ + l] = mx;
  psm[h * (NBH * LSEQ) + bh * LSEQ + l] = sm;
}

// ---------------- K2b: combine halves -> M; also zero ctx ----------------
__global__ __launch_bounds__(256) void k2b_combine(
    const float* __restrict__ pmx, const float* __restrict__ psm,
    float* __restrict__ M, float* __restrict__ ctx) {
  int t = blockIdx.x * 256 + threadIdx.x;      // 640 blocks -> 163840 threads
  if (t < NBH * LSEQ) {
    float mx = fmaxf(pmx[t], pmx[NBH * LSEQ + t]);
    float sm = psm[t] + psm[NBH * LSEQ + t];
    M[t] = mx - sm * (1.0f / (float)LSEQ);
  }
  ctx[t] = 0.f;                                 // t < CTX_ELEMS == 163840 exactly
}

// ---------------- K3: top-40 per head; M in regs, shfl + LDS reduce ----------------
// desc value, tie -> smaller index (matches jax.lax.top_k stability)
__global__ __launch_bounds__(256) void k3_topk(const float* __restrict__ M,
                                               int* __restrict__ Mtop) {
  int bh = blockIdx.x;
  int t = threadIdx.x;
  int w = t >> 6;
  int lane = t & 63;
  float v[8];
#pragma unroll
  for (int j = 0; j < 8; ++j) v[j] = M[bh * LSEQ + t + 256 * j];   // i = t + 256*j
  __shared__ float swv[4];
  __shared__ int   swi[4];
  __shared__ int   win;
  for (int it = 0; it < UU; ++it) {
    float bv = -INFINITY; int bi = 0x7fffffff;
#pragma unroll
    for (int j = 0; j < 8; ++j) {
      if (v[j] > bv) { bv = v[j]; bi = t + 256 * j; }  // ascending i: first wins ties
    }
#pragma unroll
    for (int off = 32; off > 0; off >>= 1) {
      float ov = __shfl_xor(bv, off, 64);
      int   oi = __shfl_xor(bi, off, 64);
      if (ov > bv || (ov == bv && oi < bi)) { bv = ov; bi = oi; }
    }
    if (lane == 0) { swv[w] = bv; swi[w] = bi; }
    __syncthreads();
    if (t == 0) {
      float fv = swv[0]; int fi = swi[0];
#pragma unroll
      for (int j = 1; j < 4; ++j) {
        if (swv[j] > fv || (swv[j] == fv && swi[j] < fi)) { fv = swv[j]; fi = swi[j]; }
      }
      Mtop[bh * UU + it] = fi;
      win = fi;
    }
    __syncthreads();
    int wi = win;
    if ((wi & 255) == t) v[wi >> 8] = -INFINITY;
  }
}

// ---------------- K4: scores[bh,u,l] = scale * q[Mtop[u]] . k[l] ----------------
__global__ __launch_bounds__(256) void k4_scores(
    const float* __restrict__ q, const float* __restrict__ k,
    const int* __restrict__ Mtop, float* __restrict__ attn) {
  int b = blockIdx.x;               // 512 blocks
  int bh = b & 63;
  int chunk = b >> 6;
  int l = chunk * 256 + threadIdx.x;
  const float4* kr = (const float4*)(k + (size_t)(bh * LSEQ + l) * DDIM);
  float4 kv[16];
#pragma unroll
  for (int i = 0; i < 16; ++i) kv[i] = kr[i];
  for (int u = 0; u < UU; ++u) {
    int qi = __builtin_amdgcn_readfirstlane(Mtop[bh * UU + u]);
    const float4* qr = (const float4*)(q + (size_t)(bh * LSEQ + qi) * DDIM);
    float a0 = 0.f, a1 = 0.f, a2 = 0.f, a3 = 0.f;
#pragma unroll
    for (int i = 0; i < 16; i += 4) {
      float4 x0 = qr[i], x1 = qr[i+1], x2 = qr[i+2], x3 = qr[i+3];
      float4 y0 = kv[i], y1 = kv[i+1], y2 = kv[i+2], y3 = kv[i+3];
      a0 += x0.x*y0.x + x0.y*y0.y + x0.z*y0.z + x0.w*y0.w;
      a1 += x1.x*y1.x + x1.y*y1.y + x1.z*y1.z + x1.w*y1.w;
      a2 += x2.x*y2.x + x2.y*y2.y + x2.z*y2.z + x2.w*y2.w;
      a3 += x3.x*y3.x + x3.y*y3.y + x3.z*y3.z + x3.w*y3.w;
    }
    attn[(size_t)(bh * UU + u) * LSEQ + l] = ((a0+a1)+(a2+a3)) * 0.125f;
  }
}

// ---------------- K5: softmax over l for each (bh,u) row, in place ----------------
__global__ __launch_bounds__(256) void k5_softmax(float* __restrict__ attn) {
  __shared__ float red[256];
  int row = blockIdx.x;                       // NBH*UU rows
  float* p = attn + (size_t)row * LSEQ;
  int t = threadIdx.x;
  float v[8];
  float mx = -INFINITY;
#pragma unroll
  for (int i = 0; i < 8; ++i) { v[i] = p[t + 256 * i]; mx = fmaxf(mx, v[i]); }
  red[t] = mx; __syncthreads();
  for (int off = 128; off > 0; off >>= 1) {
    if (t < off) red[t] = fmaxf(red[t], red[t + off]);
    __syncthreads();
  }
  mx = red[0]; __syncthreads();
  float sm = 0.f;
#pragma unroll
  for (int i = 0; i < 8; ++i) { v[i] = __expf(v[i] - mx); sm += v[i]; }
  red[t] = sm; __syncthreads();
  for (int off = 128; off > 0; off >>= 1) {
    if (t < off) red[t] += red[t + off];
    __syncthreads();
  }
  float inv = 1.0f / red[0];
#pragma unroll
  for (int i = 0; i < 8; ++i) p[t + 256 * i] = v[i] * inv;
}

// ---------------- K7: context[bh,u,d] += sum_l attn[bh,u,l] * v[bh,l,d] ----------------
// 512 blocks: bh = b&63, l-eighth = b>>6 (256 l). v tile staged in 64KB LDS once;
// wave w owns u-group w*10..w*10+10 (attn rows read once per block, broadcast loads).
// fp32 atomicAdd into ctx (zeroed by k2b).
__global__ __launch_bounds__(256) void k7_context(
    const float* __restrict__ attn, const float* __restrict__ v,
    float* __restrict__ ctx) {
  __shared__ float vt[256 * DDIM];   // 64KB
  int b = blockIdx.x;
  int bh = b & 63;
  int l0 = (b >> 6) * 256;
  int t = threadIdx.x;

  const float4* src = (const float4*)(v + ((size_t)bh * LSEQ + l0) * DDIM);
  float4* dst = (float4*)vt;
#pragma unroll
  for (int i = 0; i < 16; ++i) dst[t + 256 * i] = src[t + 256 * i];
  __syncthreads();

  int w = t >> 6;
  int d = t & 63;
  const float* ab = attn + ((size_t)bh * UU + w * 10) * LSEQ + l0;
  float acc[10];
#pragma unroll
  for (int u = 0; u < 10; ++u) acc[u] = 0.f;
#pragma unroll 1
  for (int l4 = 0; l4 < 64; ++l4) {
    int l = l4 * 4;
    float4 av[10];
#pragma unroll
    for (int u = 0; u < 10; ++u)
      av[u] = *(const float4*)(ab + (size_t)u * LSEQ + l);   // 64 lanes same addr -> broadcast
#pragma unroll
    for (int i = 0; i < 4; ++i) {
      float vv = vt[(l + i) * DDIM + d];
#pragma unroll
      for (int u = 0; u < 10; ++u)
        acc[u] = fmaf(((const float*)&av[u])[i], vv, acc[u]);
    }
  }
#pragma unroll
  for (int u = 0; u < 10; ++u)
    atomicAdd(&ctx[((size_t)bh * UU + w * 10 + u) * DDIM + d], acc[u]);
}

extern "C" void kernel_launch(void* const* d_in, const int* in_sizes, int n_in,
                              void* d_out, int out_size, void* d_ws, size_t ws_size,
                              hipStream_t stream) {
  const float* q   = (const float*)d_in[0];
  const float* k   = (const float*)d_in[1];
  const float* v   = (const float*)d_in[2];
  const int*   idx = (const int*)d_in[3];

  float* ctx  = (float*)d_out;                  // [NBH, UU, DDIM]
  float* attn = (float*)d_out + CTX_ELEMS;      // [NBH, UU, LSEQ]

  // ws layout: M | Mtop | pmx[2] | psm[2]   (~2.6 MB)
  float* M    = (float*)d_ws;                                    // 131072 f
  int*   Mtop = (int*)(M + NBH * LSEQ);                          // 2560 i
  float* pmx  = (float*)(Mtop + NBH * UU);                       // 2*131072 f
  float* psm  = pmx + 2 * NBH * LSEQ;                            // 2*131072 f

  k12_sample_m<<<NBH * 16, 256, 0, stream>>>(q, k, idx, pmx, psm);
  k2b_combine<<<640, 256, 0, stream>>>(pmx, psm, M, ctx);
  k3_topk<<<NBH, 256, 0, stream>>>(M, Mtop);
  k4_scores<<<NBH * 8, 256, 0, stream>>>(q, k, Mtop, attn);
  k5_softmax<<<NBH * UU, 256, 0, stream>>>(attn);
  k7_context<<<NBH * 8, 256, 0, stream>>>(attn, v, ctx);
}

// Round 4
// 312.267 us; speedup vs baseline: 1.8139x; 1.4159x over previous
//
#include <hip/hip_runtime.h>
#include <math.h>

// ProbAttention (Informer ProbSparse) — B=8 L=2048 H=8 D=64 u=40
// q/k/v reshape(B,H,L,D) is a flat reinterpretation -> treat as (BH=64, L, D) contiguous.
#define LSEQ 2048
#define DDIM 64
#define UU   40
#define NBH  64
#define CTX_ELEMS (NBH*UU*DDIM)   // 163840

// ---------------- K12: fused QK_sample + M, 16-lanes-per-l geometry ----------------
// 8192 blocks: bh = b&63, ltile = b>>6 (16 l per block). Thread = (lid = t>>4, lane = t&15).
// Each sampled k-row read = 16 contiguous lanes x float4 = 256B coalesced segment
// (4 segments/wave-inst instead of 64 scattered lines). Dot = 4-step shfl_xor butterfly
// within the 16-lane group. Also zeroes ctx (first 640 blocks).
__global__ __launch_bounds__(256, 8) void k12_sample_m(
    const float* __restrict__ q, const float* __restrict__ k,
    const int* __restrict__ idxs, float* __restrict__ M, float* __restrict__ ctx) {
  int b = blockIdx.x;
  int bh = b & 63;
  int ltile = b >> 6;
  int t = threadIdx.x;
  int lid = t >> 4;
  int lane = t & 15;
  int l = ltile * 16 + lid;

  int gt = b * 256 + t;
  if (gt < CTX_ELEMS) ctx[gt] = 0.f;

  float4 qv = *(const float4*)(q + ((size_t)(bh * LSEQ + l)) * DDIM + lane * 4);
  const float* kbase = k + (size_t)bh * LSEQ * DDIM;
  const int4* ir = (const int4*)(idxs + l * UU);   // 160B rows -> 16B aligned

  float mx = -INFINITY, sm = 0.f;
#pragma unroll 1
  for (int s4 = 0; s4 < UU / 4; ++s4) {
    int4 jv = ir[s4];
    float4 k0 = *(const float4*)(kbase + (size_t)jv.x * DDIM + lane * 4);
    float4 k1 = *(const float4*)(kbase + (size_t)jv.y * DDIM + lane * 4);
    float4 k2 = *(const float4*)(kbase + (size_t)jv.z * DDIM + lane * 4);
    float4 k3 = *(const float4*)(kbase + (size_t)jv.w * DDIM + lane * 4);
    float d0 = qv.x * k0.x + qv.y * k0.y + qv.z * k0.z + qv.w * k0.w;
    float d1 = qv.x * k1.x + qv.y * k1.y + qv.z * k1.z + qv.w * k1.w;
    float d2 = qv.x * k2.x + qv.y * k2.y + qv.z * k2.z + qv.w * k2.w;
    float d3 = qv.x * k3.x + qv.y * k3.y + qv.z * k3.z + qv.w * k3.w;
#pragma unroll
    for (int off = 1; off < 16; off <<= 1) {
      d0 += __shfl_xor(d0, off, 64);
      d1 += __shfl_xor(d1, off, 64);
      d2 += __shfl_xor(d2, off, 64);
      d3 += __shfl_xor(d3, off, 64);
    }
    mx = fmaxf(fmaxf(fmaxf(mx, d0), fmaxf(d1, d2)), d3);
    sm += (d0 + d1) + (d2 + d3);
  }
  if (lane == 0) M[bh * LSEQ + l] = mx - sm * (1.0f / (float)LSEQ);
}

// ---------------- K3: top-40 per head; M in regs, shfl + LDS reduce ----------------
// desc value, tie -> smaller index (matches jax.lax.top_k stability)
__global__ __launch_bounds__(256) void k3_topk(const float* __restrict__ M,
                                               int* __restrict__ Mtop) {
  int bh = blockIdx.x;
  int t = threadIdx.x;
  int w = t >> 6;
  int lane = t & 63;
  float v[8];
#pragma unroll
  for (int j = 0; j < 8; ++j) v[j] = M[bh * LSEQ + t + 256 * j];   // i = t + 256*j
  __shared__ float swv[4];
  __shared__ int   swi[4];
  __shared__ int   win;
  for (int it = 0; it < UU; ++it) {
    float bv = -INFINITY; int bi = 0x7fffffff;
#pragma unroll
    for (int j = 0; j < 8; ++j) {
      if (v[j] > bv) { bv = v[j]; bi = t + 256 * j; }  // ascending i: first wins ties
    }
#pragma unroll
    for (int off = 32; off > 0; off >>= 1) {
      float ov = __shfl_xor(bv, off, 64);
      int   oi = __shfl_xor(bi, off, 64);
      if (ov > bv || (ov == bv && oi < bi)) { bv = ov; bi = oi; }
    }
    if (lane == 0) { swv[w] = bv; swi[w] = bi; }
    __syncthreads();
    if (t == 0) {
      float fv = swv[0]; int fi = swi[0];
#pragma unroll
      for (int j = 1; j < 4; ++j) {
        if (swv[j] > fv || (swv[j] == fv && swi[j] < fi)) { fv = swv[j]; fi = swi[j]; }
      }
      Mtop[bh * UU + it] = fi;
      win = fi;
    }
    __syncthreads();
    int wi = win;
    if ((wi & 255) == t) v[wi >> 8] = -INFINITY;
  }
}

// ---------------- K4: scores[bh,u,l] = scale * q[Mtop[u]] . k[l] ----------------
// 1024 blocks: bh = b&63, l-chunk = (b>>6)&7, u-half = b>>9 (20 u each) -> 4 waves/EU.
__global__ __launch_bounds__(256, 4) void k4_scores(
    const float* __restrict__ q, const float* __restrict__ k,
    const int* __restrict__ Mtop, float* __restrict__ attn) {
  int b = blockIdx.x;
  int bh = b & 63;
  int chunk = (b >> 6) & 7;
  int u0 = (b >> 9) * 20;
  int l = chunk * 256 + threadIdx.x;
  const float4* kr = (const float4*)(k + (size_t)(bh * LSEQ + l) * DDIM);
  float4 kv[16];
#pragma unroll
  for (int i = 0; i < 16; ++i) kv[i] = kr[i];
  for (int u = u0; u < u0 + 20; ++u) {
    int qi = __builtin_amdgcn_readfirstlane(Mtop[bh * UU + u]);
    const float4* qr = (const float4*)(q + (size_t)(bh * LSEQ + qi) * DDIM);
    float a0 = 0.f, a1 = 0.f, a2 = 0.f, a3 = 0.f;
#pragma unroll
    for (int i = 0; i < 16; i += 4) {
      float4 x0 = qr[i], x1 = qr[i+1], x2 = qr[i+2], x3 = qr[i+3];
      float4 y0 = kv[i], y1 = kv[i+1], y2 = kv[i+2], y3 = kv[i+3];
      a0 += x0.x*y0.x + x0.y*y0.y + x0.z*y0.z + x0.w*y0.w;
      a1 += x1.x*y1.x + x1.y*y1.y + x1.z*y1.z + x1.w*y1.w;
      a2 += x2.x*y2.x + x2.y*y2.y + x2.z*y2.z + x2.w*y2.w;
      a3 += x3.x*y3.x + x3.y*y3.y + x3.z*y3.z + x3.w*y3.w;
    }
    attn[(size_t)(bh * UU + u) * LSEQ + l] = ((a0+a1)+(a2+a3)) * 0.125f;
  }
}

// ---------------- K5: softmax over l for each (bh,u) row, in place ----------------
__global__ __launch_bounds__(256) void k5_softmax(float* __restrict__ attn) {
  __shared__ float red[256];
  int row = blockIdx.x;                       // NBH*UU rows
  float* p = attn + (size_t)row * LSEQ;
  int t = threadIdx.x;
  float v[8];
  float mx = -INFINITY;
#pragma unroll
  for (int i = 0; i < 8; ++i) { v[i] = p[t + 256 * i]; mx = fmaxf(mx, v[i]); }
  red[t] = mx; __syncthreads();
  for (int off = 128; off > 0; off >>= 1) {
    if (t < off) red[t] = fmaxf(red[t], red[t + off]);
    __syncthreads();
  }
  mx = red[0]; __syncthreads();
  float sm = 0.f;
#pragma unroll
  for (int i = 0; i < 8; ++i) { v[i] = __expf(v[i] - mx); sm += v[i]; }
  red[t] = sm; __syncthreads();
  for (int off = 128; off > 0; off >>= 1) {
    if (t < off) red[t] += red[t + off];
    __syncthreads();
  }
  float inv = 1.0f / red[0];
#pragma unroll
  for (int i = 0; i < 8; ++i) p[t + 256 * i] = v[i] * inv;
}

// ---------------- K7: context[bh,u,d] += sum_l attn[bh,u,l] * v[bh,l,d] ----------------
// 512 blocks: bh = b&63, l-eighth = b>>6 (256 l). v tile staged in 64KB LDS once;
// wave w owns u-group w*10..w*10+10 (attn rows read once per block, broadcast loads).
// fp32 atomicAdd into ctx (zeroed by k12).
__global__ __launch_bounds__(256) void k7_context(
    const float* __restrict__ attn, const float* __restrict__ v,
    float* __restrict__ ctx) {
  __shared__ float vt[256 * DDIM];   // 64KB
  int b = blockIdx.x;
  int bh = b & 63;
  int l0 = (b >> 6) * 256;
  int t = threadIdx.x;

  const float4* src = (const float4*)(v + ((size_t)bh * LSEQ + l0) * DDIM);
  float4* dst = (float4*)vt;
#pragma unroll
  for (int i = 0; i < 16; ++i) dst[t + 256 * i] = src[t + 256 * i];
  __syncthreads();

  int w = t >> 6;
  int d = t & 63;
  const float* ab = attn + ((size_t)bh * UU + w * 10) * LSEQ + l0;
  float acc[10];
#pragma unroll
  for (int u = 0; u < 10; ++u) acc[u] = 0.f;
#pragma unroll 1
  for (int l4 = 0; l4 < 64; ++l4) {
    int l = l4 * 4;
    float4 av[10];
#pragma unroll
    for (int u = 0; u < 10; ++u)
      av[u] = *(const float4*)(ab + (size_t)u * LSEQ + l);   // 64 lanes same addr -> broadcast
#pragma unroll
    for (int i = 0; i < 4; ++i) {
      float vv = vt[(l + i) * DDIM + d];
#pragma unroll
      for (int u = 0; u < 10; ++u)
        acc[u] = fmaf(((const float*)&av[u])[i], vv, acc[u]);
    }
  }
#pragma unroll
  for (int u = 0; u < 10; ++u)
    atomicAdd(&ctx[((size_t)bh * UU + w * 10 + u) * DDIM + d], acc[u]);
}

extern "C" void kernel_launch(void* const* d_in, const int* in_sizes, int n_in,
                              void* d_out, int out_size, void* d_ws, size_t ws_size,
                              hipStream_t stream) {
  const float* q   = (const float*)d_in[0];
  const float* k   = (const float*)d_in[1];
  const float* v   = (const float*)d_in[2];
  const int*   idx = (const int*)d_in[3];

  float* ctx  = (float*)d_out;                  // [NBH, UU, DDIM]
  float* attn = (float*)d_out + CTX_ELEMS;      // [NBH, UU, LSEQ]

  // ws layout: M | Mtop  (~522 KB)
  float* M    = (float*)d_ws;                                    // 131072 f
  int*   Mtop = (int*)(M + NBH * LSEQ);                          // 2560 i

  k12_sample_m<<<NBH * 128, 256, 0, stream>>>(q, k, idx, M, ctx);
  k3_topk<<<NBH, 256, 0, stream>>>(M, Mtop);
  k4_scores<<<NBH * 16, 256, 0, stream>>>(q, k, Mtop, attn);
  k5_softmax<<<NBH * UU, 256, 0, stream>>>(attn);
  k7_context<<<NBH * 8, 256, 0, stream>>>(attn, v, ctx);
}